// Round 1
// baseline (10688.927 us; speedup 1.0000x reference)
//
#include <hip/hip_runtime.h>
#include <hip/hip_bf16.h>
#include <math.h>

// Problem constants
// B=4, C=16 -> N=64 images; E=256 channels; H=W=32 -> HW=1024; I=256; HID=1024; L=4
// ws layout (f32): h[64][256][1024] @0 (64MB), t[64][1024][256] @64MB (NHWC),
// w1t[4][256e][1024d] @128MB, w2t[4][1024d][256e] @132MB, gx @136MB (256KB),
// nx @+256KB, cvec @+512KB (4KB), flag @+516KB. Total ~137MB.

__device__ __forceinline__ float block_sum(float v, float* red) {
#pragma unroll
  for (int o = 32; o > 0; o >>= 1) v += __shfl_down(v, o);
  int lane = threadIdx.x & 63, w = threadIdx.x >> 6;
  int nw = blockDim.x >> 6;
  if (lane == 0) red[w] = v;
  __syncthreads();
  if (threadIdx.x == 0) {
    float s = 0.f;
    for (int i = 0; i < nw; ++i) s += red[i];
    red[0] = s;
  }
  __syncthreads();
  float s = red[0];
  __syncthreads();
  return s;
}

// ---- prep: transpose fc1_w -> w1t[l][e][d], fc2_w -> w2t[l][d][e]
__global__ void k_prep_transpose(const float* __restrict__ fc1w, const float* __restrict__ fc2w,
                                 float* __restrict__ w1t, float* __restrict__ w2t) {
  int i = blockIdx.x * 256 + threadIdx.x;  // over 4*262144
  int l = i >> 18;
  int r = i & 262143;
  // fc1w: [l][d(1024)][e(256)]
  int d = r >> 8, e = r & 255;
  w1t[((l * 256 + e) << 10) + d] = fc1w[i];
  // fc2w: [l][e(256)][d(1024)]
  int e2 = r >> 10, d2 = r & 1023;
  w2t[((l << 10) + d2) * 256 + e2] = fc2w[i];
}

// ---- prep: flag[l] = any(grn_g != 0); cvec[l][e] = sum_d fc2_w[l][e][d]*grn_b[l][d]
__global__ void k_prep_misc(const float* __restrict__ grng, const float* __restrict__ grnb,
                            const float* __restrict__ fc2w, int* __restrict__ flag,
                            float* __restrict__ cvec) {
  __shared__ float red[8];
  int l = blockIdx.y;
  if (blockIdx.x == 0) {
    float any = 0.f;
    for (int d = threadIdx.x; d < 1024; d += 256)
      any += (grng[l * 1024 + d] != 0.f) ? 1.f : 0.f;
    float tot = block_sum(any, red);
    if (threadIdx.x == 0) flag[l] = (tot > 0.f) ? 1 : 0;
  } else {
    int e = blockIdx.x - 1;
    float s = 0.f;
    for (int d = threadIdx.x; d < 1024; d += 256)
      s += fc2w[((l * 256 + e) << 10) + d] * grnb[l * 1024 + d];
    float tot = block_sum(s, red);
    if (threadIdx.x == 0) cvec[l * 256 + e] = tot;
  }
}

__global__ void k_zero(float* __restrict__ p, int n) {
  int i = blockIdx.x * 256 + threadIdx.x;
  if (i < n) p[i] = 0.f;
}

// ---- hyperkernel: h[n][e][p] = sum_i x[b][i][p] * hk_w[idx[n]][i*256+e] + hk_b[idx[n]][e]
__global__ void __launch_bounds__(256) k_hyper(const float* __restrict__ x, const int* __restrict__ idx,
                                               const float* __restrict__ hkw, const float* __restrict__ hkb,
                                               float* __restrict__ h) {
  // grid (16 ptiles, 4 etiles, 64 n); block 256
  __shared__ float As[16][64];
  __shared__ float Bs[16][64];
  int n = blockIdx.z;
  int b = n >> 4;
  int ch = idx[n];
  const float* W = hkw + (size_t)ch * 65536;    // [i][e]
  const float* X = x + (size_t)b * 262144;      // [i][p]
  int e0 = blockIdx.y * 64, p0 = blockIdx.x * 64;
  int tid = threadIdx.x;
  int tx = tid & 15, ty = tid >> 4;  // tx->p group, ty->e group
  float acc[4][4];
#pragma unroll
  for (int i = 0; i < 4; ++i)
#pragma unroll
    for (int j = 0; j < 4; ++j) acc[i][j] = 0.f;
  for (int k0 = 0; k0 < 256; k0 += 16) {
    for (int i = tid; i < 1024; i += 256) {
      int ki = i >> 6, c = i & 63;
      As[ki][c] = W[(k0 + ki) * 256 + e0 + c];
      Bs[ki][c] = X[(k0 + ki) * 1024 + p0 + c];
    }
    __syncthreads();
#pragma unroll
    for (int ki = 0; ki < 16; ++ki) {
      float a0 = As[ki][ty * 4 + 0], a1 = As[ki][ty * 4 + 1], a2 = As[ki][ty * 4 + 2], a3 = As[ki][ty * 4 + 3];
      float b0 = Bs[ki][tx * 4 + 0], b1 = Bs[ki][tx * 4 + 1], b2 = Bs[ki][tx * 4 + 2], b3 = Bs[ki][tx * 4 + 3];
      acc[0][0] += a0 * b0; acc[0][1] += a0 * b1; acc[0][2] += a0 * b2; acc[0][3] += a0 * b3;
      acc[1][0] += a1 * b0; acc[1][1] += a1 * b1; acc[1][2] += a1 * b2; acc[1][3] += a1 * b3;
      acc[2][0] += a2 * b0; acc[2][1] += a2 * b1; acc[2][2] += a2 * b2; acc[2][3] += a2 * b3;
      acc[3][0] += a3 * b0; acc[3][1] += a3 * b1; acc[3][2] += a3 * b2; acc[3][3] += a3 * b3;
    }
    __syncthreads();
  }
#pragma unroll
  for (int i = 0; i < 4; ++i) {
    int e = e0 + ty * 4 + i;
    float bias = hkb[ch * 256 + e];
    float4 v = make_float4(acc[i][0] + bias, acc[i][1] + bias, acc[i][2] + bias, acc[i][3] + bias);
    *(float4*)&h[((size_t)n * 256 + e) * 1024 + p0 + tx * 4] = v;
  }
}

// ---- depthwise 7x7 conv, NCHW in -> NHWC out (t), + dw_b
__global__ void __launch_bounds__(256) k_conv(const float* __restrict__ h, const float* __restrict__ dww,
                                              const float* __restrict__ dwb, float* __restrict__ t, int l) {
  // grid (4 ychunk, 256 e, 64 n), block (32,8)
  int n = blockIdx.z, e = blockIdx.y;
  int y = blockIdx.x * 8 + threadIdx.y, xx = threadIdx.x;
  const float* plane = h + ((size_t)n * 256 + e) * 1024;
  const float* wv = dww + ((size_t)l * 256 + e) * 49;
  float acc = dwb[l * 256 + e];
#pragma unroll
  for (int ky = 0; ky < 7; ++ky) {
    int yy = y + ky - 3;
    if (yy < 0 || yy >= 32) continue;
#pragma unroll
    for (int kx = 0; kx < 7; ++kx) {
      int xc = xx + kx - 3;
      if (xc < 0 || xc >= 32) continue;
      acc += plane[yy * 32 + xc] * wv[ky * 7 + kx];
    }
  }
  t[((size_t)n * 1024 + y * 32 + xx) * 256 + e] = acc;
}

// ---- fused LN + fc1 + GELU (+GRN scale) + fc2 + residual. MODE 0: gx accumulation pass only.
template <int MODE>
__global__ void __launch_bounds__(256) k_mlp(
    const float* __restrict__ t, const float* __restrict__ lng, const float* __restrict__ lnb,
    const float* __restrict__ w1t, const float* __restrict__ fc1b,
    const float* __restrict__ grng, const float* __restrict__ nx,
    const float* __restrict__ w2t, const float* __restrict__ fc2b,
    const float* __restrict__ cvec, float* __restrict__ h,
    float* __restrict__ gx, const int* __restrict__ flag, int l) {
  if (MODE == 0 && flag[l] == 0) return;
  __shared__ float tIn[32][257];
  __shared__ float uS[32][133];
  __shared__ float w1S[16][128];
  __shared__ float w2S[16][256];
  __shared__ float muS[32], rsS[32];
  int n = blockIdx.y;
  int p0 = blockIdx.x * 32;
  int tid = threadIdx.x;
  // load 32 pixel rows
  const float* tb = t + ((size_t)(n * 1024 + p0)) * 256;
  for (int i = tid; i < 32 * 256; i += 256) tIn[i >> 8][i & 255] = tb[i];
  __syncthreads();
  // LayerNorm per pixel over E=256
  {
    int j = tid & 7, p = tid >> 3;
    float s = 0.f, sq = 0.f;
    for (int e = j; e < 256; e += 8) {
      float v = tIn[p][e];
      s += v; sq += v * v;
    }
    s += __shfl_xor(s, 1); sq += __shfl_xor(sq, 1);
    s += __shfl_xor(s, 2); sq += __shfl_xor(sq, 2);
    s += __shfl_xor(s, 4); sq += __shfl_xor(sq, 4);
    if (j == 0) {
      float mu = s * (1.f / 256.f);
      float var = sq * (1.f / 256.f) - mu * mu;
      muS[p] = mu;
      rsS[p] = rsqrtf(fmaxf(var, 0.f) + 1e-5f);
    }
  }
  __syncthreads();
  for (int i = tid; i < 32 * 256; i += 256) {
    int p = i >> 8, e = i & 255;
    tIn[p][e] = (tIn[p][e] - muS[p]) * rsS[p] * lng[l * 256 + e] + lnb[l * 256 + e];
  }
  __syncthreads();

  const float* w1p = w1t + l * 262144;
  const float* w2p = w2t + l * 262144;
  int pg = tid & 7, dg = tid >> 3;  // GEMM1: p=pg*4.., d=dg*4..; GEMM2: e=dg*8..
  float acc2[4][8];
  if (MODE == 1) {
#pragma unroll
    for (int i = 0; i < 4; ++i)
#pragma unroll
      for (int j = 0; j < 8; ++j) acc2[i][j] = 0.f;
  }
  for (int dc = 0; dc < 8; ++dc) {
    // GEMM1: u[32p][128d] = tIn[32p][256e] @ w1t[e][d]
    float acc1[4][4];
#pragma unroll
    for (int i = 0; i < 4; ++i)
#pragma unroll
      for (int j = 0; j < 4; ++j) acc1[i][j] = 0.f;
    for (int k0 = 0; k0 < 256; k0 += 16) {
      for (int i = tid; i < 2048; i += 256) {
        int ki = i >> 7, dd = i & 127;
        w1S[ki][dd] = w1p[(k0 + ki) * 1024 + dc * 128 + dd];
      }
      __syncthreads();
#pragma unroll
      for (int ki = 0; ki < 16; ++ki) {
        float a0 = tIn[pg * 4 + 0][k0 + ki];
        float a1 = tIn[pg * 4 + 1][k0 + ki];
        float a2 = tIn[pg * 4 + 2][k0 + ki];
        float a3 = tIn[pg * 4 + 3][k0 + ki];
        float4 w = *(const float4*)&w1S[ki][dg * 4];
        acc1[0][0] += a0 * w.x; acc1[0][1] += a0 * w.y; acc1[0][2] += a0 * w.z; acc1[0][3] += a0 * w.w;
        acc1[1][0] += a1 * w.x; acc1[1][1] += a1 * w.y; acc1[1][2] += a1 * w.z; acc1[1][3] += a1 * w.w;
        acc1[2][0] += a2 * w.x; acc1[2][1] += a2 * w.y; acc1[2][2] += a2 * w.z; acc1[2][3] += a2 * w.w;
        acc1[3][0] += a3 * w.x; acc1[3][1] += a3 * w.y; acc1[3][2] += a3 * w.z; acc1[3][3] += a3 * w.w;
      }
      __syncthreads();
    }
    // bias + exact GELU (+alpha) -> uS
#pragma unroll
    for (int j = 0; j < 4; ++j) {
      int d = dc * 128 + dg * 4 + j;
      float bsv = fc1b[l * 1024 + d];
      float al = 1.f;
      if (MODE == 1) al = 1.f + grng[l * 1024 + d] * nx[n * 1024 + d];
#pragma unroll
      for (int i = 0; i < 4; ++i) {
        float u = acc1[i][j] + bsv;
        float g = 0.5f * u * (1.f + erff(u * 0.70710678118f));
        uS[pg * 4 + i][dg * 4 + j] = (MODE == 1) ? g * al : g;
      }
    }
    __syncthreads();
    if (MODE == 0) {
      if (tid < 128) {
        float s = 0.f;
#pragma unroll
        for (int p = 0; p < 32; ++p) { float v = uS[p][tid]; s += v * v; }
        atomicAdd(&gx[n * 1024 + dc * 128 + tid], s);
      }
      __syncthreads();
      continue;
    }
    // GEMM2: acc2[32p][256e] += uS[32p][128d] @ w2t[d][e]
    for (int k0 = 0; k0 < 128; k0 += 16) {
      for (int i = tid; i < 4096; i += 256) {
        int ki = i >> 8, e = i & 255;
        w2S[ki][e] = w2p[(dc * 128 + k0 + ki) * 256 + e];
      }
      __syncthreads();
#pragma unroll
      for (int ki = 0; ki < 16; ++ki) {
        float u0 = uS[pg * 4 + 0][k0 + ki];
        float u1 = uS[pg * 4 + 1][k0 + ki];
        float u2 = uS[pg * 4 + 2][k0 + ki];
        float u3 = uS[pg * 4 + 3][k0 + ki];
        float4 wa = *(const float4*)&w2S[ki][dg * 8];
        float4 wb = *(const float4*)&w2S[ki][dg * 8 + 4];
        acc2[0][0] += u0 * wa.x; acc2[0][1] += u0 * wa.y; acc2[0][2] += u0 * wa.z; acc2[0][3] += u0 * wa.w;
        acc2[0][4] += u0 * wb.x; acc2[0][5] += u0 * wb.y; acc2[0][6] += u0 * wb.z; acc2[0][7] += u0 * wb.w;
        acc2[1][0] += u1 * wa.x; acc2[1][1] += u1 * wa.y; acc2[1][2] += u1 * wa.z; acc2[1][3] += u1 * wa.w;
        acc2[1][4] += u1 * wb.x; acc2[1][5] += u1 * wb.y; acc2[1][6] += u1 * wb.z; acc2[1][7] += u1 * wb.w;
        acc2[2][0] += u2 * wa.x; acc2[2][1] += u2 * wa.y; acc2[2][2] += u2 * wa.z; acc2[2][3] += u2 * wa.w;
        acc2[2][4] += u2 * wb.x; acc2[2][5] += u2 * wb.y; acc2[2][6] += u2 * wb.z; acc2[2][7] += u2 * wb.w;
        acc2[3][0] += u3 * wa.x; acc2[3][1] += u3 * wa.y; acc2[3][2] += u3 * wa.z; acc2[3][3] += u3 * wa.w;
        acc2[3][4] += u3 * wb.x; acc2[3][5] += u3 * wb.y; acc2[3][6] += u3 * wb.z; acc2[3][7] += u3 * wb.w;
      }
      __syncthreads();
    }
  }
  if (MODE == 1) {
    // epilogue: + fc2_b + cvec + residual -> h
#pragma unroll
    for (int j = 0; j < 8; ++j) {
      int e = dg * 8 + j;
      float add = fc2b[l * 256 + e] + cvec[l * 256 + e];
      float* hp = &h[((size_t)n * 256 + e) * 1024 + p0 + pg * 4];
#pragma unroll
      for (int i = 0; i < 4; ++i) hp[i] = acc2[i][j] + add + hp[i];
    }
  }
}

// ---- nx[n][d] = sqrt(gx) / (mean_d sqrt(gx) + 1e-6); 0 if flag==0
__global__ void k_nx(const float* __restrict__ gx, float* __restrict__ nx,
                     const int* __restrict__ flag, int l) {
  int n = blockIdx.x, tid = threadIdx.x;
  if (flag[l] == 0) {
    for (int d = tid; d < 1024; d += 256) nx[n * 1024 + d] = 0.f;
    return;
  }
  __shared__ float red[8];
  __shared__ float sv[1024];
  float s = 0.f;
  for (int d = tid; d < 1024; d += 256) {
    float v = sqrtf(gx[n * 1024 + d]);
    sv[d] = v; s += v;
  }
  float tot = block_sum(s, red);
  float mean = tot * (1.f / 1024.f);
  for (int d = tid; d < 1024; d += 256) nx[n * 1024 + d] = sv[d] / (mean + 1e-6f);
}

// ---- pred 1x1 conv + pixel shuffle
__global__ void __launch_bounds__(256) k_pred(const float* __restrict__ h, const float* __restrict__ pw,
                                              const float* __restrict__ pb, float* __restrict__ out) {
  // grid (4 pchunk, 64 n); block 256
  __shared__ float wS[32][256];
  int n = blockIdx.y;
  int p = blockIdx.x * 256 + threadIdx.x;
  for (int i = threadIdx.x; i < 32 * 256; i += 256) wS[i >> 8][i & 255] = pw[i];
  __syncthreads();
  float acc[32];
#pragma unroll
  for (int o = 0; o < 32; ++o) acc[o] = pb[o];
  const float* hb = h + (size_t)n * 262144 + p;
  for (int e = 0; e < 256; ++e) {
    float hv = hb[e << 10];
#pragma unroll
    for (int o = 0; o < 32; ++o) acc[o] += hv * wS[o][e];
  }
  int y = p >> 5, xx = p & 31;
#pragma unroll
  for (int o = 0; o < 32; ++o) {
    int s1 = o >> 3, s2 = (o >> 1) & 3, tt = o & 1;
    size_t oi = (((size_t)n * 128 + y * 4 + s1) * 128 + xx * 4 + s2) * 2 + tt;
    out[oi] = acc[o];
  }
}

extern "C" void kernel_launch(void* const* d_in, const int* in_sizes, int n_in,
                              void* d_out, int out_size, void* d_ws, size_t ws_size,
                              hipStream_t stream) {
  const float* x    = (const float*)d_in[0];
  const int*   idx  = (const int*)d_in[1];
  const float* hkw  = (const float*)d_in[2];
  const float* hkb  = (const float*)d_in[3];
  const float* dww  = (const float*)d_in[4];
  const float* dwb  = (const float*)d_in[5];
  const float* lng  = (const float*)d_in[6];
  const float* lnb  = (const float*)d_in[7];
  const float* fc1w = (const float*)d_in[8];
  const float* fc1b = (const float*)d_in[9];
  const float* grng = (const float*)d_in[10];
  const float* grnb = (const float*)d_in[11];
  const float* fc2w = (const float*)d_in[12];
  const float* fc2b = (const float*)d_in[13];
  const float* pw   = (const float*)d_in[14];
  const float* pb   = (const float*)d_in[15];
  float* out = (float*)d_out;

  char* ws = (char*)d_ws;
  float* h    = (float*)(ws);
  float* t    = (float*)(ws + ((size_t)64 << 20));
  float* w1t  = (float*)(ws + ((size_t)128 << 20));
  float* w2t  = (float*)(ws + ((size_t)132 << 20));
  float* gx   = (float*)(ws + ((size_t)136 << 20));
  float* nx   = (float*)(ws + ((size_t)136 << 20) + (1 << 18));
  float* cvec = (float*)(ws + ((size_t)136 << 20) + (2 << 18));
  int*   flag = (int*)  (ws + ((size_t)136 << 20) + (2 << 18) + 4096);

  k_prep_transpose<<<4096, 256, 0, stream>>>(fc1w, fc2w, w1t, w2t);
  k_prep_misc<<<dim3(257, 4), 256, 0, stream>>>(grng, grnb, fc2w, flag, cvec);
  k_hyper<<<dim3(16, 4, 64), 256, 0, stream>>>(x, idx, hkw, hkb, h);
  for (int l = 0; l < 4; ++l) {
    k_conv<<<dim3(4, 256, 64), dim3(32, 8), 0, stream>>>(h, dww, dwb, t, l);
    k_zero<<<256, 256, 0, stream>>>(gx, 65536);
    k_mlp<0><<<dim3(32, 64), 256, 0, stream>>>(t, lng, lnb, w1t, fc1b, grng, nx, w2t, fc2b, cvec, h, gx, flag, l);
    k_nx<<<64, 256, 0, stream>>>(gx, nx, flag, l);
    k_mlp<1><<<dim3(32, 64), 256, 0, stream>>>(t, lng, lnb, w1t, fc1b, grng, nx, w2t, fc2b, cvec, h, gx, flag, l);
  }
  k_pred<<<dim3(4, 64), 256, 0, stream>>>(h, pw, pb, out);
}

// Round 3
// 2421.702 us; speedup vs baseline: 4.4138x; 4.4138x over previous
//
#include <hip/hip_runtime.h>
#include <hip/hip_bf16.h>
#include <math.h>

// B=4, C=16 -> N=64 images; E=256; H=W=32 -> P=1024/img, 65536 total; I=256; HID=1024; L=4
// ws layout (fits < 133MB; round-0 proved ws_size >= ~136.5MB):
//   h    f32 [64][256][1024]  @0      64MB   residual stream (NCHW)
//   tb   bf16[65536][256]     @64MB   32MB   conv out NHWC; LayerNorm'd IN PLACE
//   u    bf16[16384][1024]    @96MB   32MB   hidden chunk (16 images)
//     overlay (prologue only): Wt bf16[64][256][256] @96MB (8MB); xTb bf16[4][1024][256] @104MB (2MB)
//   w1b  bf16[4][1024][256]   @128MB  2MB
//   w2b  bf16[4][256][1024]   @130MB  2MB
//   gx   f32[64][1024]        @132MB  256KB; nx @+256KB; cvec @+512KB (4KB); flag @+516KB

typedef __attribute__((ext_vector_type(8))) __bf16 bf16x8;
typedef __attribute__((ext_vector_type(4))) float f32x4;

__device__ __forceinline__ short f2bf(float f) {
  unsigned u = __float_as_uint(f);
  unsigned r = (u + 0x7FFFu + ((u >> 16) & 1u)) >> 16;
  return (short)r;
}
__device__ __forceinline__ float bf2f(short s) {
  return __uint_as_float(((unsigned)(unsigned short)s) << 16);
}
__device__ __forceinline__ int pack2(short a, short b) {
  return (int)(unsigned short)a | ((int)(unsigned short)b << 16);
}
__device__ __forceinline__ float gelu(float x) {
  return 0.5f * x * (1.f + erff(x * 0.70710678118f));
}

__device__ __forceinline__ float block_sum(float v, float* red) {
#pragma unroll
  for (int o = 32; o > 0; o >>= 1) v += __shfl_down(v, o);
  int lane = threadIdx.x & 63, w = threadIdx.x >> 6;
  int nw = blockDim.x >> 6;
  if (lane == 0) red[w] = v;
  __syncthreads();
  if (threadIdx.x == 0) {
    float s = 0.f;
    for (int i = 0; i < nw; ++i) s += red[i];
    red[0] = s;
  }
  __syncthreads();
  float s = red[0];
  __syncthreads();
  return s;
}

// ======================= MFMA GEMM core =======================
// C[m][n] = sum_k A[m][k]*Bt[n][k]; 128x128 tile, 4 waves, 4x4 16x16x32 frags.
// A,Bt bf16 (short), K contiguous. LDS rows padded to 40 shorts (80B) -> b128-friendly.
template <int K>
__device__ __forceinline__ void gemm_core(const short* __restrict__ A, const short* __restrict__ Bt,
                                          int m0, int n0, short* As, short* Bs, f32x4 acc[4][4]) {
  const int tid = threadIdx.x;
  const int lane = tid & 63, wave = tid >> 6;
  const int wr = wave >> 1, wc = wave & 1;
  const int lr = lane & 15, kg = lane >> 4;
#pragma unroll
  for (int mi = 0; mi < 4; ++mi)
#pragma unroll
    for (int ni = 0; ni < 4; ++ni) acc[mi][ni] = f32x4{0.f, 0.f, 0.f, 0.f};
  const int r0 = tid >> 2, kp = (tid & 3) * 8;
  for (int k0 = 0; k0 < K; k0 += 32) {
    *(int4*)&As[r0 * 40 + kp]        = *(const int4*)&A[(size_t)(m0 + r0) * K + k0 + kp];
    *(int4*)&As[(r0 + 64) * 40 + kp] = *(const int4*)&A[(size_t)(m0 + r0 + 64) * K + k0 + kp];
    *(int4*)&Bs[r0 * 40 + kp]        = *(const int4*)&Bt[(size_t)(n0 + r0) * K + k0 + kp];
    *(int4*)&Bs[(r0 + 64) * 40 + kp] = *(const int4*)&Bt[(size_t)(n0 + r0 + 64) * K + k0 + kp];
    __syncthreads();
    bf16x8 af[4], bfr[4];
#pragma unroll
    for (int mi = 0; mi < 4; ++mi) af[mi] = *(const bf16x8*)&As[(wr * 64 + mi * 16 + lr) * 40 + kg * 8];
#pragma unroll
    for (int ni = 0; ni < 4; ++ni) bfr[ni] = *(const bf16x8*)&Bs[(wc * 64 + ni * 16 + lr) * 40 + kg * 8];
#pragma unroll
    for (int mi = 0; mi < 4; ++mi)
#pragma unroll
      for (int ni = 0; ni < 4; ++ni)
        acc[mi][ni] = __builtin_amdgcn_mfma_f32_16x16x32_bf16(af[mi], bfr[ni], acc[mi][ni], 0, 0, 0);
    __syncthreads();
  }
}

// ======================= prep kernels =======================
__global__ void k_cvt_w(const float* __restrict__ fc1w, const float* __restrict__ fc2w,
                        short* __restrict__ w1b, short* __restrict__ w2b) {
  int i = blockIdx.x * 256 + threadIdx.x;  // 4*262144
  w1b[i] = f2bf(fc1w[i]);
  w2b[i] = f2bf(fc2w[i]);
}

// x [4][256 i][1024 p] f32 -> xTb [4][1024 p][256 i] bf16
__global__ void k_prep_xt(const float* __restrict__ x, short* __restrict__ xTb) {
  __shared__ float tile[32][33];
  int tx = threadIdx.x & 31, ty = threadIdx.x >> 5;
  int p0 = blockIdx.x * 32, i0 = blockIdx.y * 32, b = blockIdx.z;
#pragma unroll
  for (int r = 0; r < 4; ++r) {
    int i = ty + r * 8;
    tile[i][tx] = x[((size_t)b * 256 + i0 + i) * 1024 + p0 + tx];
  }
  __syncthreads();
#pragma unroll
  for (int r = 0; r < 4; ++r) {
    int p = ty + r * 8;
    xTb[((size_t)b * 1024 + p0 + p) * 256 + i0 + tx] = f2bf(tile[tx][p]);
  }
}

// hk_w gather+transpose: Wt[n][e][i] bf16 = hkw[idx[n]][i][e]
__global__ void k_prep_wt(const float* __restrict__ hkw, const int* __restrict__ idx,
                          short* __restrict__ Wt) {
  __shared__ float tile[32][33];
  int tx = threadIdx.x & 31, ty = threadIdx.x >> 5;
  int e0 = blockIdx.x * 32, i0 = blockIdx.y * 32, n = blockIdx.z;
  int ch = idx[n];
#pragma unroll
  for (int r = 0; r < 4; ++r) {
    int i = ty + r * 8;
    tile[i][tx] = hkw[(size_t)ch * 65536 + (size_t)(i0 + i) * 256 + e0 + tx];
  }
  __syncthreads();
#pragma unroll
  for (int r = 0; r < 4; ++r) {
    int e = ty + r * 8;
    Wt[((size_t)n * 256 + e0 + e) * 256 + i0 + tx] = f2bf(tile[tx][e]);
  }
}

// flag[l] = any(grn_g != 0); cvec[l][e] = sum_d fc2_w[l][e][d]*grn_b[l][d]
__global__ void k_prep_misc(const float* __restrict__ grng, const float* __restrict__ grnb,
                            const float* __restrict__ fc2w, int* __restrict__ flag,
                            float* __restrict__ cvec) {
  __shared__ float red[8];
  int l = blockIdx.y;
  if (blockIdx.x == 0) {
    float any = 0.f;
    for (int d = threadIdx.x; d < 1024; d += 256)
      any += (grng[l * 1024 + d] != 0.f) ? 1.f : 0.f;
    float tot = block_sum(any, red);
    if (threadIdx.x == 0) flag[l] = (tot > 0.f) ? 1 : 0;
  } else {
    int e = blockIdx.x - 1;
    float s = 0.f;
    for (int d = threadIdx.x; d < 1024; d += 256)
      s += fc2w[((size_t)(l * 256 + e) << 10) + d] * grnb[l * 1024 + d];
    float tot = block_sum(s, red);
    if (threadIdx.x == 0) cvec[l * 256 + e] = tot;
  }
}

// ======================= hyper GEMM: h[n][e][p] = Wt[n]@xTb[b] + hkb =======================
__global__ void __launch_bounds__(256) k_hypm(const short* __restrict__ Wt, const short* __restrict__ xTb,
                                              const int* __restrict__ idx, const float* __restrict__ hkb,
                                              float* __restrict__ h) {
  __shared__ short As[5120], Bs[5120];
  f32x4 acc[4][4];
  int n = blockIdx.z;
  int m0 = blockIdx.y * 128, n0 = blockIdx.x * 128;
  gemm_core<256>(Wt + (size_t)n * 65536, xTb + (size_t)(n >> 4) * 262144, m0, n0, As, Bs, acc);
  int ch = idx[n];
  const int lane = threadIdx.x & 63, wave = threadIdx.x >> 6;
  const int wr = wave >> 1, wc = wave & 1, lr = lane & 15, kg = lane >> 4;
#pragma unroll
  for (int mi = 0; mi < 4; ++mi) {
    int ebase = m0 + wr * 64 + mi * 16 + kg * 4;
#pragma unroll
    for (int ni = 0; ni < 4; ++ni) {
      int p = n0 + wc * 64 + ni * 16 + lr;
      f32x4 v = acc[mi][ni];
#pragma unroll
      for (int r = 0; r < 4; ++r)
        h[((size_t)(n * 256 + ebase + r) << 10) + p] = v[r] + hkb[ch * 256 + ebase + r];
    }
  }
}

// ======================= depthwise 7x7 conv (h NCHW f32 -> tb NHWC bf16) =======================
__global__ void __launch_bounds__(256) k_conv(const float* __restrict__ h, const float* __restrict__ dww,
                                              const float* __restrict__ dwb, short* __restrict__ tb, int l) {
  int n = blockIdx.z, e = blockIdx.y;
  int y = blockIdx.x * 8 + threadIdx.y, xx = threadIdx.x;
  const float* plane = h + ((size_t)n * 256 + e) * 1024;
  const float* wv = dww + ((size_t)l * 256 + e) * 49;
  float acc = dwb[l * 256 + e];
#pragma unroll
  for (int ky = 0; ky < 7; ++ky) {
    int yy = y + ky - 3;
    if (yy < 0 || yy >= 32) continue;
#pragma unroll
    for (int kx = 0; kx < 7; ++kx) {
      int xc = xx + kx - 3;
      if (xc < 0 || xc >= 32) continue;
      acc += plane[yy * 32 + xc] * wv[ky * 7 + kx];
    }
  }
  tb[((size_t)n * 1024 + y * 32 + xx) * 256 + e] = f2bf(acc);
}

// ======================= LayerNorm IN PLACE on tb (bf16) =======================
__global__ void __launch_bounds__(256) k_ln(short* __restrict__ tb, const float* __restrict__ lng,
                                            const float* __restrict__ lnb, int l) {
  int pix = blockIdx.x * 8 + (threadIdx.x >> 5);
  int j = threadIdx.x & 31;
  short* row = tb + (size_t)pix * 256;
  int4 pk = *(const int4*)&row[j * 8];
  short sh[8];
  *(int4*)sh = pk;
  float vv[8];
#pragma unroll
  for (int i = 0; i < 8; ++i) vv[i] = bf2f(sh[i]);
  float s = 0.f, q = 0.f;
#pragma unroll
  for (int i = 0; i < 8; ++i) { s += vv[i]; q += vv[i] * vv[i]; }
#pragma unroll
  for (int m = 1; m <= 16; m <<= 1) { s += __shfl_xor(s, m); q += __shfl_xor(q, m); }
  float mu = s * (1.f / 256.f);
  float var = q * (1.f / 256.f) - mu * mu;
  float rs = rsqrtf(fmaxf(var, 0.f) + 1e-5f);
  short o[8];
#pragma unroll
  for (int i = 0; i < 8; ++i) {
    int e = j * 8 + i;
    o[i] = f2bf((vv[i] - mu) * rs * lng[l * 256 + e] + lnb[l * 256 + e]);
  }
  int4 po;
  po.x = pack2(o[0], o[1]); po.y = pack2(o[2], o[3]);
  po.z = pack2(o[4], o[5]); po.w = pack2(o[6], o[7]);
  *(int4*)&row[j * 8] = po;
}

// ======================= GRN general path (flag-gated; no-op for this data) ==============
__global__ void k_gzero(float* __restrict__ gx, const int* __restrict__ flag, int l) {
  if (flag[l] == 0) return;
  int i = blockIdx.x * 256 + threadIdx.x;
  if (i < 65536) gx[i] = 0.f;
}

// full-image fc1 recompute, accumulate gx[n][d] = sum_p gelu(...)^2  (only when flag==1)
__global__ void __launch_bounds__(256) k_gx1(const short* __restrict__ w1b, const short* __restrict__ tb,
                                             const float* __restrict__ fc1b, float* __restrict__ gx,
                                             const int* __restrict__ flag, int l) {
  if (flag[l] == 0) return;
  __shared__ short As[5120], Bs[5120];
  f32x4 acc[4][4];
  int m0 = blockIdx.y * 128, n0 = blockIdx.x * 128;
  gemm_core<256>(w1b + (size_t)l * 262144, tb, m0, n0, As, Bs, acc);
  const int lane = threadIdx.x & 63, wave = threadIdx.x >> 6;
  const int wr = wave >> 1, wc = wave & 1, lr = lane & 15, kg = lane >> 4;
  int n = (n0 >> 10);
#pragma unroll
  for (int mi = 0; mi < 4; ++mi) {
    int dbase = m0 + wr * 64 + mi * 16 + kg * 4;
#pragma unroll
    for (int ni = 0; ni < 4; ++ni) {
      f32x4 v = acc[mi][ni];
#pragma unroll
      for (int r = 0; r < 4; ++r) {
        float g = gelu(v[r] + fc1b[l * 1024 + dbase + r]);
        atomicAdd(&gx[n * 1024 + dbase + r], g * g);
      }
    }
  }
}

// nx[n][d] = sqrt(gx)/(mean_d sqrt(gx)+1e-6); zeroed when flag==0
__global__ void k_nx(const float* __restrict__ gx, float* __restrict__ nx,
                     const int* __restrict__ flag, int l) {
  int n = blockIdx.x, tid = threadIdx.x;
  if (flag[l] == 0) {
    for (int d = tid; d < 1024; d += 256) nx[n * 1024 + d] = 0.f;
    return;
  }
  __shared__ float red[8];
  __shared__ float sv[1024];
  float s = 0.f;
  for (int d = tid; d < 1024; d += 256) {
    float v = sqrtf(gx[n * 1024 + d]);
    sv[d] = v; s += v;
  }
  float tot = block_sum(s, red);
  float mean = tot * (1.f / 1024.f);
  for (int d = tid; d < 1024; d += 256) nx[n * 1024 + d] = sv[d] / (mean + 1e-6f);
}

// ======================= fc1 (chunked): u[pl][d] = gelu(tb@W1^T+b1)*(1+g*nx) ==============
__global__ void __launch_bounds__(256) k_fc1(const short* __restrict__ w1b, const short* __restrict__ tb,
                                             const float* __restrict__ fc1b, const float* __restrict__ grng,
                                             const float* __restrict__ nx, short* __restrict__ u,
                                             int l, int cbase) {
  __shared__ short As[5120], Bs[5120];
  f32x4 acc[4][4];
  int m0 = blockIdx.y * 128, n0 = blockIdx.x * 128;
  gemm_core<256>(w1b + (size_t)l * 262144, tb + (size_t)cbase * 256, m0, n0, As, Bs, acc);
  const int lane = threadIdx.x & 63, wave = threadIdx.x >> 6;
  const int wr = wave >> 1, wc = wave & 1, lr = lane & 15, kg = lane >> 4;
  int nimg = (cbase + n0) >> 10;
#pragma unroll
  for (int mi = 0; mi < 4; ++mi) {
    int dbase = m0 + wr * 64 + mi * 16 + kg * 4;
    float b0 = fc1b[l * 1024 + dbase + 0], b1 = fc1b[l * 1024 + dbase + 1];
    float b2 = fc1b[l * 1024 + dbase + 2], b3 = fc1b[l * 1024 + dbase + 3];
    float a0 = 1.f + grng[l * 1024 + dbase + 0] * nx[nimg * 1024 + dbase + 0];
    float a1 = 1.f + grng[l * 1024 + dbase + 1] * nx[nimg * 1024 + dbase + 1];
    float a2 = 1.f + grng[l * 1024 + dbase + 2] * nx[nimg * 1024 + dbase + 2];
    float a3 = 1.f + grng[l * 1024 + dbase + 3] * nx[nimg * 1024 + dbase + 3];
#pragma unroll
    for (int ni = 0; ni < 4; ++ni) {
      int pl = n0 + wc * 64 + ni * 16 + lr;  // local pixel in chunk
      f32x4 v = acc[mi][ni];
      short4 sv;
      sv.x = f2bf(gelu(v[0] + b0) * a0);
      sv.y = f2bf(gelu(v[1] + b1) * a1);
      sv.z = f2bf(gelu(v[2] + b2) * a2);
      sv.w = f2bf(gelu(v[3] + b3) * a3);
      *(short4*)&u[(size_t)pl * 1024 + dbase] = sv;
    }
  }
}

// ======================= fc2 (chunked): h += u@W2^T + b2 + cvec =======================
__global__ void __launch_bounds__(256) k_fc2(const short* __restrict__ w2b, const short* __restrict__ u,
                                             const float* __restrict__ fc2b, const float* __restrict__ cvec,
                                             float* __restrict__ h, int l, int cbase) {
  __shared__ short As[5120], Bs[5120];
  f32x4 acc[4][4];
  int m0 = blockIdx.y * 128, n0 = blockIdx.x * 128;
  gemm_core<1024>(w2b + (size_t)l * 262144, u, m0, n0, As, Bs, acc);
  const int lane = threadIdx.x & 63, wave = threadIdx.x >> 6;
  const int wr = wave >> 1, wc = wave & 1, lr = lane & 15, kg = lane >> 4;
#pragma unroll
  for (int mi = 0; mi < 4; ++mi) {
    int ebase = m0 + wr * 64 + mi * 16 + kg * 4;
    float add0 = fc2b[l * 256 + ebase + 0] + cvec[l * 256 + ebase + 0];
    float add1 = fc2b[l * 256 + ebase + 1] + cvec[l * 256 + ebase + 1];
    float add2 = fc2b[l * 256 + ebase + 2] + cvec[l * 256 + ebase + 2];
    float add3 = fc2b[l * 256 + ebase + 3] + cvec[l * 256 + ebase + 3];
#pragma unroll
    for (int ni = 0; ni < 4; ++ni) {
      int P = cbase + n0 + wc * 64 + ni * 16 + lr;
      int n = P >> 10, p = P & 1023;
      f32x4 v = acc[mi][ni];
      float* hp0 = &h[((size_t)(n * 256 + ebase) << 10) + p];
      hp0[0]       = v[0] + add0 + hp0[0];
      hp0[1 << 10] = v[1] + add1 + hp0[1 << 10];
      hp0[2 << 10] = v[2] + add2 + hp0[2 << 10];
      hp0[3 << 10] = v[3] + add3 + hp0[3 << 10];
    }
  }
}

// ======================= pred 1x1 conv + pixel shuffle =======================
__global__ void __launch_bounds__(256) k_pred(const float* __restrict__ h, const float* __restrict__ pw,
                                              const float* __restrict__ pb, float* __restrict__ out) {
  __shared__ float wS[32][256];
  int n = blockIdx.y;
  int p = blockIdx.x * 256 + threadIdx.x;
  for (int i = threadIdx.x; i < 32 * 256; i += 256) wS[i >> 8][i & 255] = pw[i];
  __syncthreads();
  float acc[32];
#pragma unroll
  for (int o = 0; o < 32; ++o) acc[o] = pb[o];
  const float* hb = h + (size_t)n * 262144 + p;
  for (int e = 0; e < 256; ++e) {
    float hv = hb[e << 10];
#pragma unroll
    for (int o = 0; o < 32; ++o) acc[o] += hv * wS[o][e];
  }
  int y = p >> 5, xx = p & 31;
#pragma unroll
  for (int o = 0; o < 32; ++o) {
    int s1 = o >> 3, s2 = (o >> 1) & 3, tt = o & 1;
    size_t oi = (((size_t)n * 128 + y * 4 + s1) * 128 + xx * 4 + s2) * 2 + tt;
    out[oi] = acc[o];
  }
}

extern "C" void kernel_launch(void* const* d_in, const int* in_sizes, int n_in,
                              void* d_out, int out_size, void* d_ws, size_t ws_size,
                              hipStream_t stream) {
  const float* x    = (const float*)d_in[0];
  const int*   idx  = (const int*)d_in[1];
  const float* hkw  = (const float*)d_in[2];
  const float* hkb  = (const float*)d_in[3];
  const float* dww  = (const float*)d_in[4];
  const float* dwb  = (const float*)d_in[5];
  const float* lng  = (const float*)d_in[6];
  const float* lnb  = (const float*)d_in[7];
  const float* fc1w = (const float*)d_in[8];
  const float* fc1b = (const float*)d_in[9];
  const float* grng = (const float*)d_in[10];
  const float* grnb = (const float*)d_in[11];
  const float* fc2w = (const float*)d_in[12];
  const float* fc2b = (const float*)d_in[13];
  const float* pw   = (const float*)d_in[14];
  const float* pb   = (const float*)d_in[15];
  float* out = (float*)d_out;

  char* ws = (char*)d_ws;
  float* h    = (float*)(ws);
  short* tb   = (short*)(ws + (64ull << 20));
  short* u    = (short*)(ws + (96ull << 20));
  short* Wt   = (short*)(ws + (96ull << 20));            // overlay (prologue only)
  short* xTb  = (short*)(ws + (104ull << 20));           // overlay (prologue only)
  short* w1b  = (short*)(ws + (128ull << 20));
  short* w2b  = (short*)(ws + (130ull << 20));
  float* gx   = (float*)(ws + (132ull << 20));
  float* nx   = (float*)(ws + (132ull << 20) + (1 << 18));
  float* cvec = (float*)(ws + (132ull << 20) + (2 << 18));
  int*   flag = (int*)  (ws + (132ull << 20) + (2 << 18) + 4096);

  k_cvt_w<<<4096, 256, 0, stream>>>(fc1w, fc2w, w1b, w2b);
  k_prep_misc<<<dim3(257, 4), 256, 0, stream>>>(grng, grnb, fc2w, flag, cvec);
  k_prep_xt<<<dim3(32, 8, 4), 256, 0, stream>>>(x, xTb);
  k_prep_wt<<<dim3(8, 8, 64), 256, 0, stream>>>(hkw, idx, Wt);
  k_hypm<<<dim3(8, 2, 64), 256, 0, stream>>>(Wt, xTb, idx, hkb, h);
  for (int l = 0; l < 4; ++l) {
    k_conv<<<dim3(4, 256, 64), dim3(32, 8), 0, stream>>>(h, dww, dwb, tb, l);
    k_ln<<<8192, 256, 0, stream>>>(tb, lng, lnb, l);
    k_gzero<<<256, 256, 0, stream>>>(gx, flag, l);
    k_gx1<<<dim3(512, 8), 256, 0, stream>>>(w1b, tb, fc1b, gx, flag, l);
    k_nx<<<64, 256, 0, stream>>>(gx, nx, flag, l);
    for (int c = 0; c < 4; ++c) {
      int cbase = c * 16384;
      k_fc1<<<dim3(128, 8), 256, 0, stream>>>(w1b, tb, fc1b, grng, nx, u, l, cbase);
      k_fc2<<<dim3(128, 2), 256, 0, stream>>>(w2b, u, fc2b, cvec, h, l, cbase);
    }
  }
  k_pred<<<dim3(4, 64), 256, 0, stream>>>(h, pw, pb, out);
}

// Round 4
// 1246.176 us; speedup vs baseline: 8.5774x; 1.9433x over previous
//
#include <hip/hip_runtime.h>
#include <hip/hip_bf16.h>
#include <math.h>

// B=4, C=16 -> N=64 images; E=256; H=W=32 -> P=1024/img, 65536 total; I=256; HID=1024; L=4
// ws layout (~132.6MB, < proven-safe 136.5MB):
//   h    f32 [64][256][1024]  @0      64MB   residual stream (NCHW)
//   tb   bf16[65536][256]     @64MB   32MB   LN'd activations NHWC (fc1 input)
//   u    bf16[16384][1024]    @96MB   32MB   hidden chunk (16 images)
//     overlays in u region: tc bf16[64][256][1024] (conv out NCHW, dead before fc1 writes u);
//                           Wt bf16[64][256][256] @96MB; xTb bf16[4][1024][256] @104MB (prologue only)
//   w1b  bf16[4][1024][256]   @128MB  2MB
//   w2b  bf16[4][256][1024]   @130MB  2MB
//   gx   f32[64][1024]        @132MB  256KB; nx @+256KB; cvec @+512KB (4KB); flag @+516KB

typedef __attribute__((ext_vector_type(8))) __bf16 bf16x8;
typedef __attribute__((ext_vector_type(4))) float f32x4;

__device__ __forceinline__ short f2bf(float f) {
  unsigned u = __float_as_uint(f);
  unsigned r = (u + 0x7FFFu + ((u >> 16) & 1u)) >> 16;
  return (short)r;
}
__device__ __forceinline__ float bf2f(short s) {
  return __uint_as_float(((unsigned)(unsigned short)s) << 16);
}
__device__ __forceinline__ int pack2(short a, short b) {
  return (int)(unsigned short)a | ((int)(unsigned short)b << 16);
}
__device__ __forceinline__ float gelu(float x) {
  return 0.5f * x * (1.f + erff(x * 0.70710678118f));
}

__device__ __forceinline__ float block_sum(float v, float* red) {
#pragma unroll
  for (int o = 32; o > 0; o >>= 1) v += __shfl_down(v, o);
  int lane = threadIdx.x & 63, w = threadIdx.x >> 6;
  int nw = blockDim.x >> 6;
  if (lane == 0) red[w] = v;
  __syncthreads();
  if (threadIdx.x == 0) {
    float s = 0.f;
    for (int i = 0; i < nw; ++i) s += red[i];
    red[0] = s;
  }
  __syncthreads();
  float s = red[0];
  __syncthreads();
  return s;
}

// ======================= MFMA GEMM core =======================
// C[m][n] = sum_k A[m][k]*Bt[n][k]; 128x128 tile, 4 waves, 4x4 16x16x32 frags.
template <int K>
__device__ __forceinline__ void gemm_core(const short* __restrict__ A, const short* __restrict__ Bt,
                                          int m0, int n0, short* As, short* Bs, f32x4 acc[4][4]) {
  const int tid = threadIdx.x;
  const int lane = tid & 63, wave = tid >> 6;
  const int wr = wave >> 1, wc = wave & 1;
  const int lr = lane & 15, kg = lane >> 4;
#pragma unroll
  for (int mi = 0; mi < 4; ++mi)
#pragma unroll
    for (int ni = 0; ni < 4; ++ni) acc[mi][ni] = f32x4{0.f, 0.f, 0.f, 0.f};
  const int r0 = tid >> 2, kp = (tid & 3) * 8;
  for (int k0 = 0; k0 < K; k0 += 32) {
    *(int4*)&As[r0 * 40 + kp]        = *(const int4*)&A[(size_t)(m0 + r0) * K + k0 + kp];
    *(int4*)&As[(r0 + 64) * 40 + kp] = *(const int4*)&A[(size_t)(m0 + r0 + 64) * K + k0 + kp];
    *(int4*)&Bs[r0 * 40 + kp]        = *(const int4*)&Bt[(size_t)(n0 + r0) * K + k0 + kp];
    *(int4*)&Bs[(r0 + 64) * 40 + kp] = *(const int4*)&Bt[(size_t)(n0 + r0 + 64) * K + k0 + kp];
    __syncthreads();
    bf16x8 af[4], bfr[4];
#pragma unroll
    for (int mi = 0; mi < 4; ++mi) af[mi] = *(const bf16x8*)&As[(wr * 64 + mi * 16 + lr) * 40 + kg * 8];
#pragma unroll
    for (int ni = 0; ni < 4; ++ni) bfr[ni] = *(const bf16x8*)&Bs[(wc * 64 + ni * 16 + lr) * 40 + kg * 8];
#pragma unroll
    for (int mi = 0; mi < 4; ++mi)
#pragma unroll
      for (int ni = 0; ni < 4; ++ni)
        acc[mi][ni] = __builtin_amdgcn_mfma_f32_16x16x32_bf16(af[mi], bfr[ni], acc[mi][ni], 0, 0, 0);
    __syncthreads();
  }
}

// ======================= prep kernels =======================
__global__ void k_cvt_w(const float* __restrict__ fc1w, const float* __restrict__ fc2w,
                        short* __restrict__ w1b, short* __restrict__ w2b) {
  int i = blockIdx.x * 256 + threadIdx.x;  // 4*262144
  w1b[i] = f2bf(fc1w[i]);
  w2b[i] = f2bf(fc2w[i]);
}

// x [4][256 i][1024 p] f32 -> xTb [4][1024 p][256 i] bf16
__global__ void k_prep_xt(const float* __restrict__ x, short* __restrict__ xTb) {
  __shared__ float tile[32][33];
  int tx = threadIdx.x & 31, ty = threadIdx.x >> 5;
  int p0 = blockIdx.x * 32, i0 = blockIdx.y * 32, b = blockIdx.z;
#pragma unroll
  for (int r = 0; r < 4; ++r) {
    int i = ty + r * 8;
    tile[i][tx] = x[((size_t)b * 256 + i0 + i) * 1024 + p0 + tx];
  }
  __syncthreads();
#pragma unroll
  for (int r = 0; r < 4; ++r) {
    int p = ty + r * 8;
    xTb[((size_t)b * 1024 + p0 + p) * 256 + i0 + tx] = f2bf(tile[tx][p]);
  }
}

// hk_w gather+transpose: Wt[n][e][i] bf16 = hkw[idx[n]][i][e]
__global__ void k_prep_wt(const float* __restrict__ hkw, const int* __restrict__ idx,
                          short* __restrict__ Wt) {
  __shared__ float tile[32][33];
  int tx = threadIdx.x & 31, ty = threadIdx.x >> 5;
  int e0 = blockIdx.x * 32, i0 = blockIdx.y * 32, n = blockIdx.z;
  int ch = idx[n];
#pragma unroll
  for (int r = 0; r < 4; ++r) {
    int i = ty + r * 8;
    tile[i][tx] = hkw[(size_t)ch * 65536 + (size_t)(i0 + i) * 256 + e0 + tx];
  }
  __syncthreads();
#pragma unroll
  for (int r = 0; r < 4; ++r) {
    int e = ty + r * 8;
    Wt[((size_t)n * 256 + e0 + e) * 256 + i0 + tx] = f2bf(tile[tx][e]);
  }
}

// flag[l] = any(grn_g != 0); cvec[l][e] = sum_d fc2_w[l][e][d]*grn_b[l][d]
__global__ void k_prep_misc(const float* __restrict__ grng, const float* __restrict__ grnb,
                            const float* __restrict__ fc2w, int* __restrict__ flag,
                            float* __restrict__ cvec) {
  __shared__ float red[8];
  int l = blockIdx.y;
  if (blockIdx.x == 0) {
    float any = 0.f;
    for (int d = threadIdx.x; d < 1024; d += 256)
      any += (grng[l * 1024 + d] != 0.f) ? 1.f : 0.f;
    float tot = block_sum(any, red);
    if (threadIdx.x == 0) flag[l] = (tot > 0.f) ? 1 : 0;
  } else {
    int e = blockIdx.x - 1;
    float s = 0.f;
    for (int d = threadIdx.x; d < 1024; d += 256)
      s += fc2w[((size_t)(l * 256 + e) << 10) + d] * grnb[l * 1024 + d];
    float tot = block_sum(s, red);
    if (threadIdx.x == 0) cvec[l * 256 + e] = tot;
  }
}

// ======================= hyper GEMM: h[n][e][p] = Wt[n]@xTb[b] + hkb =======================
__global__ void __launch_bounds__(256) k_hypm(const short* __restrict__ Wt, const short* __restrict__ xTb,
                                              const int* __restrict__ idx, const float* __restrict__ hkb,
                                              float* __restrict__ h) {
  __shared__ short As[5120], Bs[5120];
  f32x4 acc[4][4];
  int n = blockIdx.z;
  int m0 = blockIdx.y * 128, n0 = blockIdx.x * 128;
  gemm_core<256>(Wt + (size_t)n * 65536, xTb + (size_t)(n >> 4) * 262144, m0, n0, As, Bs, acc);
  int ch = idx[n];
  const int lane = threadIdx.x & 63, wave = threadIdx.x >> 6;
  const int wr = wave >> 1, wc = wave & 1, lr = lane & 15, kg = lane >> 4;
#pragma unroll
  for (int mi = 0; mi < 4; ++mi) {
    int ebase = m0 + wr * 64 + mi * 16 + kg * 4;
#pragma unroll
    for (int ni = 0; ni < 4; ++ni) {
      int p = n0 + wc * 64 + ni * 16 + lr;
      f32x4 v = acc[mi][ni];
#pragma unroll
      for (int r = 0; r < 4; ++r)
        h[((size_t)(n * 256 + ebase + r) << 10) + p] = v[r] + hkb[ch * 256 + ebase + r];
    }
  }
}

// ======================= depthwise 7x7 conv: LDS-staged, NCHW f32 -> NCHW bf16 ==========
__global__ void __launch_bounds__(256) k_conv(const float* __restrict__ h, const float* __restrict__ dww,
                                              const float* __restrict__ dwb, short* __restrict__ tc, int l) {
  // grid (256 e, 64 n); block 256; 6KB LDS plane with zero halo
  __shared__ float sm[38][40];
  int e = blockIdx.x, n = blockIdx.y;
  const float* plane = h + ((size_t)(n * 256 + e)) * 1024;
  const float* wv = dww + ((size_t)(l * 256 + e)) * 49;
  float w[49];
#pragma unroll
  for (int i = 0; i < 49; ++i) w[i] = wv[i];  // uniform address -> scalar loads
  int tid = threadIdx.x;
  for (int i = tid; i < 38 * 40; i += 256) ((float*)sm)[i] = 0.f;
  __syncthreads();
  for (int i = tid; i < 1024; i += 256) sm[(i >> 5) + 3][(i & 31) + 3] = plane[i];
  __syncthreads();
  int x = tid & 31, y0 = (tid >> 5) * 4;
  float bias = dwb[l * 256 + e];
  float acc0 = bias, acc1 = bias, acc2 = bias, acc3 = bias;
#pragma unroll
  for (int r = 0; r < 10; ++r) {
#pragma unroll
    for (int c = 0; c < 7; ++c) {
      float v = sm[y0 + r][x + c];
      if (r <= 6)           acc0 += v * w[r * 7 + c];
      if (r >= 1 && r <= 7) acc1 += v * w[(r - 1) * 7 + c];
      if (r >= 2 && r <= 8) acc2 += v * w[(r - 2) * 7 + c];
      if (r >= 3)           acc3 += v * w[(r - 3) * 7 + c];
    }
  }
  short* outp = tc + (((size_t)(n * 256 + e)) << 10) + y0 * 32 + x;
  outp[0]  = f2bf(acc0);
  outp[32] = f2bf(acc1);
  outp[64] = f2bf(acc2);
  outp[96] = f2bf(acc3);
}

// ======================= LayerNorm + NCHW->NHWC transpose (tc bf16 -> tb bf16) ==========
__global__ void __launch_bounds__(256) k_ln(const short* __restrict__ tc, const float* __restrict__ lng,
                                            const float* __restrict__ lnb, short* __restrict__ tb, int l) {
  // grid (32 ptile, 64 n); block 256
  __shared__ float smT[32][260];
  __shared__ float muS[32], rsS[32];
  int n = blockIdx.y, p0 = blockIdx.x * 32;
  int tid = threadIdx.x;
  const short* base = tc + ((size_t)n << 18) + p0;
  for (int i = tid; i < 8192; i += 256) {
    int e = i >> 5, p = i & 31;
    smT[p][e] = bf2f(base[(e << 10) + p]);
  }
  __syncthreads();
  {
    int j = tid & 7, p = tid >> 3;
    float s = 0.f, q = 0.f;
#pragma unroll
    for (int i = 0; i < 32; ++i) {
      float v = smT[p][j + i * 8];
      s += v; q += v * v;
    }
    s += __shfl_xor(s, 1); q += __shfl_xor(q, 1);
    s += __shfl_xor(s, 2); q += __shfl_xor(q, 2);
    s += __shfl_xor(s, 4); q += __shfl_xor(q, 4);
    if (j == 0) {
      float mu = s * (1.f / 256.f);
      float var = q * (1.f / 256.f) - mu * mu;
      muS[p] = mu;
      rsS[p] = rsqrtf(fmaxf(var, 0.f) + 1e-5f);
    }
  }
  __syncthreads();
  for (int i = tid; i < 8192; i += 256) {
    int p = i >> 8, e = i & 255;
    float v = (smT[p][e] - muS[p]) * rsS[p] * lng[l * 256 + e] + lnb[l * 256 + e];
    tb[((size_t)(n * 1024 + p0 + p)) * 256 + e] = f2bf(v);
  }
}

// ======================= GRN general path (flag-gated; no-op for this data) ==============
__global__ void k_gzero(float* __restrict__ gx, const int* __restrict__ flag, int l) {
  if (flag[l] == 0) return;
  int i = blockIdx.x * 256 + threadIdx.x;
  if (i < 65536) gx[i] = 0.f;
}

// full-image fc1 recompute, accumulate gx[n][d] = sum_p gelu(...)^2  (only when flag==1)
__global__ void __launch_bounds__(256) k_gx1(const short* __restrict__ w1b, const short* __restrict__ tb,
                                             const float* __restrict__ fc1b, float* __restrict__ gx,
                                             const int* __restrict__ flag, int l) {
  if (flag[l] == 0) return;
  __shared__ short As[5120], Bs[5120];
  f32x4 acc[4][4];
  int m0 = blockIdx.y * 128, n0 = blockIdx.x * 128;
  gemm_core<256>(w1b + (size_t)l * 262144, tb, m0, n0, As, Bs, acc);
  const int lane = threadIdx.x & 63, wave = threadIdx.x >> 6;
  const int wr = wave >> 1, wc = wave & 1, lr = lane & 15, kg = lane >> 4;
  int n = (n0 >> 10);
#pragma unroll
  for (int mi = 0; mi < 4; ++mi) {
    int dbase = m0 + wr * 64 + mi * 16 + kg * 4;
#pragma unroll
    for (int ni = 0; ni < 4; ++ni) {
      f32x4 v = acc[mi][ni];
#pragma unroll
      for (int r = 0; r < 4; ++r) {
        float g = gelu(v[r] + fc1b[l * 1024 + dbase + r]);
        atomicAdd(&gx[n * 1024 + dbase + r], g * g);
      }
    }
  }
}

// nx[n][d] = sqrt(gx)/(mean_d sqrt(gx)+1e-6); zeroed when flag==0
__global__ void k_nx(const float* __restrict__ gx, float* __restrict__ nx,
                     const int* __restrict__ flag, int l) {
  int n = blockIdx.x, tid = threadIdx.x;
  if (flag[l] == 0) {
    for (int d = tid; d < 1024; d += 256) nx[n * 1024 + d] = 0.f;
    return;
  }
  __shared__ float red[8];
  __shared__ float sv[1024];
  float s = 0.f;
  for (int d = tid; d < 1024; d += 256) {
    float v = sqrtf(gx[n * 1024 + d]);
    sv[d] = v; s += v;
  }
  float tot = block_sum(s, red);
  float mean = tot * (1.f / 1024.f);
  for (int d = tid; d < 1024; d += 256) nx[n * 1024 + d] = sv[d] / (mean + 1e-6f);
}

// ======================= fc1 (chunked): u[pl][d] = gelu(tb@W1^T+b1)*(1+g*nx) ==============
__global__ void __launch_bounds__(256) k_fc1(const short* __restrict__ w1b, const short* __restrict__ tb,
                                             const float* __restrict__ fc1b, const float* __restrict__ grng,
                                             const float* __restrict__ nx, short* __restrict__ u,
                                             int l, int cbase) {
  __shared__ short As[5120], Bs[5120];
  f32x4 acc[4][4];
  int m0 = blockIdx.y * 128, n0 = blockIdx.x * 128;
  gemm_core<256>(w1b + (size_t)l * 262144, tb + (size_t)cbase * 256, m0, n0, As, Bs, acc);
  const int lane = threadIdx.x & 63, wave = threadIdx.x >> 6;
  const int wr = wave >> 1, wc = wave & 1, lr = lane & 15, kg = lane >> 4;
  int nimg = (cbase + n0) >> 10;
#pragma unroll
  for (int mi = 0; mi < 4; ++mi) {
    int dbase = m0 + wr * 64 + mi * 16 + kg * 4;
    float b0 = fc1b[l * 1024 + dbase + 0], b1 = fc1b[l * 1024 + dbase + 1];
    float b2 = fc1b[l * 1024 + dbase + 2], b3 = fc1b[l * 1024 + dbase + 3];
    float a0 = 1.f + grng[l * 1024 + dbase + 0] * nx[nimg * 1024 + dbase + 0];
    float a1 = 1.f + grng[l * 1024 + dbase + 1] * nx[nimg * 1024 + dbase + 1];
    float a2 = 1.f + grng[l * 1024 + dbase + 2] * nx[nimg * 1024 + dbase + 2];
    float a3 = 1.f + grng[l * 1024 + dbase + 3] * nx[nimg * 1024 + dbase + 3];
#pragma unroll
    for (int ni = 0; ni < 4; ++ni) {
      int pl = n0 + wc * 64 + ni * 16 + lr;  // local pixel in chunk
      f32x4 v = acc[mi][ni];
      short4 sv;
      sv.x = f2bf(gelu(v[0] + b0) * a0);
      sv.y = f2bf(gelu(v[1] + b1) * a1);
      sv.z = f2bf(gelu(v[2] + b2) * a2);
      sv.w = f2bf(gelu(v[3] + b3) * a3);
      *(short4*)&u[(size_t)pl * 1024 + dbase] = sv;
    }
  }
}

// ======================= fc2 (chunked): h += u@W2^T + b2 + cvec =======================
__global__ void __launch_bounds__(256) k_fc2(const short* __restrict__ w2b, const short* __restrict__ u,
                                             const float* __restrict__ fc2b, const float* __restrict__ cvec,
                                             float* __restrict__ h, int l, int cbase) {
  __shared__ short As[5120], Bs[5120];
  f32x4 acc[4][4];
  int m0 = blockIdx.y * 128, n0 = blockIdx.x * 128;
  gemm_core<1024>(w2b + (size_t)l * 262144, u, m0, n0, As, Bs, acc);
  const int lane = threadIdx.x & 63, wave = threadIdx.x >> 6;
  const int wr = wave >> 1, wc = wave & 1, lr = lane & 15, kg = lane >> 4;
#pragma unroll
  for (int mi = 0; mi < 4; ++mi) {
    int ebase = m0 + wr * 64 + mi * 16 + kg * 4;
    float add0 = fc2b[l * 256 + ebase + 0] + cvec[l * 256 + ebase + 0];
    float add1 = fc2b[l * 256 + ebase + 1] + cvec[l * 256 + ebase + 1];
    float add2 = fc2b[l * 256 + ebase + 2] + cvec[l * 256 + ebase + 2];
    float add3 = fc2b[l * 256 + ebase + 3] + cvec[l * 256 + ebase + 3];
#pragma unroll
    for (int ni = 0; ni < 4; ++ni) {
      int P = cbase + n0 + wc * 64 + ni * 16 + lr;
      int n = P >> 10, p = P & 1023;
      f32x4 v = acc[mi][ni];
      float* hp0 = &h[((size_t)(n * 256 + ebase) << 10) + p];
      hp0[0]       = v[0] + add0 + hp0[0];
      hp0[1 << 10] = v[1] + add1 + hp0[1 << 10];
      hp0[2 << 10] = v[2] + add2 + hp0[2 << 10];
      hp0[3 << 10] = v[3] + add3 + hp0[3 << 10];
    }
  }
}

// ======================= pred 1x1 conv + pixel shuffle =======================
__global__ void __launch_bounds__(256) k_pred(const float* __restrict__ h, const float* __restrict__ pw,
                                              const float* __restrict__ pb, float* __restrict__ out) {
  __shared__ float wS[32][256];
  int n = blockIdx.y;
  int p = blockIdx.x * 256 + threadIdx.x;
  for (int i = threadIdx.x; i < 32 * 256; i += 256) wS[i >> 8][i & 255] = pw[i];
  __syncthreads();
  float acc[32];
#pragma unroll
  for (int o = 0; o < 32; ++o) acc[o] = pb[o];
  const float* hb = h + (size_t)n * 262144 + p;
  for (int e = 0; e < 256; ++e) {
    float hv = hb[e << 10];
#pragma unroll
    for (int o = 0; o < 32; ++o) acc[o] += hv * wS[o][e];
  }
  int y = p >> 5, xx = p & 31;
#pragma unroll
  for (int o = 0; o < 32; ++o) {
    int s1 = o >> 3, s2 = (o >> 1) & 3, tt = o & 1;
    size_t oi = (((size_t)n * 128 + y * 4 + s1) * 128 + xx * 4 + s2) * 2 + tt;
    out[oi] = acc[o];
  }
}

extern "C" void kernel_launch(void* const* d_in, const int* in_sizes, int n_in,
                              void* d_out, int out_size, void* d_ws, size_t ws_size,
                              hipStream_t stream) {
  const float* x    = (const float*)d_in[0];
  const int*   idx  = (const int*)d_in[1];
  const float* hkw  = (const float*)d_in[2];
  const float* hkb  = (const float*)d_in[3];
  const float* dww  = (const float*)d_in[4];
  const float* dwb  = (const float*)d_in[5];
  const float* lng  = (const float*)d_in[6];
  const float* lnb  = (const float*)d_in[7];
  const float* fc1w = (const float*)d_in[8];
  const float* fc1b = (const float*)d_in[9];
  const float* grng = (const float*)d_in[10];
  const float* grnb = (const float*)d_in[11];
  const float* fc2w = (const float*)d_in[12];
  const float* fc2b = (const float*)d_in[13];
  const float* pw   = (const float*)d_in[14];
  const float* pb   = (const float*)d_in[15];
  float* out = (float*)d_out;

  char* ws = (char*)d_ws;
  float* h    = (float*)(ws);
  short* tb   = (short*)(ws + (64ull << 20));
  short* u    = (short*)(ws + (96ull << 20));
  short* tc   = (short*)(ws + (96ull << 20));            // overlay (conv->ln only)
  short* Wt   = (short*)(ws + (96ull << 20));            // overlay (prologue only)
  short* xTb  = (short*)(ws + (104ull << 20));           // overlay (prologue only)
  short* w1b  = (short*)(ws + (128ull << 20));
  short* w2b  = (short*)(ws + (130ull << 20));
  float* gx   = (float*)(ws + (132ull << 20));
  float* nx   = (float*)(ws + (132ull << 20) + (1 << 18));
  float* cvec = (float*)(ws + (132ull << 20) + (2 << 18));
  int*   flag = (int*)  (ws + (132ull << 20) + (2 << 18) + 4096);

  k_cvt_w<<<4096, 256, 0, stream>>>(fc1w, fc2w, w1b, w2b);
  k_prep_misc<<<dim3(257, 4), 256, 0, stream>>>(grng, grnb, fc2w, flag, cvec);
  k_prep_xt<<<dim3(32, 8, 4), 256, 0, stream>>>(x, xTb);
  k_prep_wt<<<dim3(8, 8, 64), 256, 0, stream>>>(hkw, idx, Wt);
  k_hypm<<<dim3(8, 2, 64), 256, 0, stream>>>(Wt, xTb, idx, hkb, h);
  for (int l = 0; l < 4; ++l) {
    k_conv<<<dim3(256, 64), 256, 0, stream>>>(h, dww, dwb, tc, l);
    k_ln<<<dim3(32, 64), 256, 0, stream>>>(tc, lng, lnb, tb, l);
    k_gzero<<<256, 256, 0, stream>>>(gx, flag, l);
    k_gx1<<<dim3(512, 8), 256, 0, stream>>>(w1b, tb, fc1b, gx, flag, l);
    k_nx<<<64, 256, 0, stream>>>(gx, nx, flag, l);
    for (int c = 0; c < 4; ++c) {
      int cbase = c * 16384;
      k_fc1<<<dim3(128, 8), 256, 0, stream>>>(w1b, tb, fc1b, grng, nx, u, l, cbase);
      k_fc2<<<dim3(128, 2), 256, 0, stream>>>(w2b, u, fc2b, cvec, h, l, cbase);
    }
  }
  k_pred<<<dim3(4, 64), 256, 0, stream>>>(h, pw, pb, out);
}